// Round 7
// baseline (345.691 us; speedup 1.0000x reference)
//
#include <hip/hip_runtime.h>
#include <hip/hip_fp16.h>

#define TAU 0.07f
#define MARGIN 0.2f
#define NSPEC 64
#define BB 8192
#define DD 256

// ---- single-kernel phase flags (device-scope atomics; ws re-poisoned per iteration) ----
#define MAGICZ 0x51u
#define MAGIC1 0x1357A5C3u

// bid layout
#define B_ZERO0   1
#define B_K5      33
#define B_K2      545
#define B_T       1057
#define B_KC      1313
#define N_WORK2   1312u   // done2 contributors: 32 zero + 512 k5 + 512 k2 + 256 T
#define N_KC      2048
#define N_TOTAL   3361

// ---------------- ws layout (bytes) ----------------
//   0      float scalars[8] [0]=triSum [1]=infoSum [2]=n_valid [3]=n_valid_i [4]=elect
//   64     int   counts[64]
//   320    int   offsets[64]
//   576    u32   flagZ0   (block0 release: zcnt/done2/scalars re-initialized)
//   580    u32   zcnt     (zero-blocks completion counter)
//   584    u32   flag1    (block0 release: memberList/counts/offsets ready)
//   588    u32   done2    (work-blocks completion counter)
//   1024   float lseRow[8192]  \
//   33792  float lseCol[8192]   | zero region [1024,133120) = 32 blocks x 258 float4
//   66560  float Ts[64][256]    |
//   132096 float T[256]        /
//   133120 int   memberList[8192]
#define WS_SCALARS 0
#define WS_COUNTS  64
#define WS_OFFSETS 320
#define WS_FLAGZ0  576
#define WS_ZCNT    580
#define WS_FLAG1   584
#define WS_DONE2   588
#define WS_LSEROW  1024
#define WS_LSECOL  33792
#define WS_TS      66560
#define WS_T       132096
#define WS_MEMBER  133120

typedef _Float16 half8 __attribute__((ext_vector_type(8)));
typedef float float4v __attribute__((ext_vector_type(4)));
typedef unsigned int uint4v __attribute__((ext_vector_type(4)));

__device__ __forceinline__ uint4v pack8(float4 a, float4 b) {
  half8 h;
  h[0] = (_Float16)a.x; h[1] = (_Float16)a.y; h[2] = (_Float16)a.z; h[3] = (_Float16)a.w;
  h[4] = (_Float16)b.x; h[5] = (_Float16)b.y; h[6] = (_Float16)b.z; h[7] = (_Float16)b.w;
  return __builtin_bit_cast(uint4v, h);
}

__device__ __forceinline__ float dot4(float4 a, float4 b) {
  return a.x * b.x + a.y * b.y + a.z * b.z + a.w * b.w;
}

__device__ __forceinline__ unsigned aload(unsigned* p) { return atomicAdd(p, 0u); }

__device__ __forceinline__ void spin1(unsigned* p, unsigned v) {
  if (threadIdx.x == 0) {
    while (aload(p) != v) __builtin_amdgcn_s_sleep(8);
  }
  __syncthreads();
}
__device__ __forceinline__ void spin2(unsigned* p1, unsigned v1, unsigned* p2, unsigned v2) {
  if (threadIdx.x == 0) {
    while (aload(p1) != v1 || aload(p2) != v2) __builtin_amdgcn_s_sleep(8);
  }
  __syncthreads();
}

__global__ void __launch_bounds__(256)
mega(const float* __restrict__ sp, const float* __restrict__ tx,
     const int* __restrict__ ids, char* __restrict__ ws, float* __restrict__ out) {
  float* scalars = (float*)(ws + WS_SCALARS);
  int* counts = (int*)(ws + WS_COUNTS);
  int* offsets = (int*)(ws + WS_OFFSETS);
  unsigned* flagZ0 = (unsigned*)(ws + WS_FLAGZ0);
  unsigned* zcnt = (unsigned*)(ws + WS_ZCNT);
  unsigned* flag1 = (unsigned*)(ws + WS_FLAG1);
  unsigned* done2 = (unsigned*)(ws + WS_DONE2);
  float* lseRow = (float*)(ws + WS_LSEROW);
  float* lseCol = (float*)(ws + WS_LSECOL);
  float* Ts = (float*)(ws + WS_TS);
  float* T = (float*)(ws + WS_T);
  int* memberList = (int*)(ws + WS_MEMBER);

  int bid = blockIdx.x, tid = threadIdx.x;

  __shared__ union {
    struct { int cnt[NSPEC]; int cur[NSPEC]; } h;              // block 0
    struct { uint4v frag[1536]; int idx[192]; } k5;            // k5 role (24 KB)
    float red[8];                                              // kC role
  } sm;

  if (bid == 0) {
    // ---- setup role: re-init flags/counters, histogram, scan, scatter, release ----
    if (tid == 0) { *zcnt = 0u; *done2 = 0u; }
    if (tid < 8) ((unsigned*)scalars)[tid] = 0u;
    if (tid < NSPEC) sm.h.cnt[tid] = 0;
    __threadfence();
    __syncthreads();
    if (tid == 0) atomicExch(flagZ0, MAGICZ);   // zero-blocks may proceed
    // histogram: 32 elements per thread
    #pragma unroll
    for (int r = 0; r < 32; ++r) atomicAdd(&sm.h.cnt[ids[r * 256 + tid]], 1);
    __syncthreads();
    if (tid < NSPEC) {  // wave 0 exactly
      int o = 0;
      for (int t = 0; t < NSPEC; ++t) o += (t < tid) ? sm.h.cnt[t] : 0;
      offsets[tid] = o;
      sm.h.cur[tid] = o;
      int c = sm.h.cnt[tid];
      counts[tid] = c;
      unsigned long long bv = __ballot(c >= 2);
      float nvi = (c >= 2 && c <= BB - 1) ? (float)c : 0.f;
      for (int o2 = 1; o2 < 64; o2 <<= 1) nvi += __shfl_xor(nvi, o2);
      if (tid == 0) {
        scalars[2] = (float)__popcll(bv);
        scalars[3] = nvi;
      }
    }
    __syncthreads();
    // scatter (any order within species is a valid permutation)
    #pragma unroll
    for (int r = 0; r < 32; ++r) {
      int i = r * 256 + tid;
      int s = ids[i];
      int pos = atomicAdd(&sm.h.cur[s], 1);
      memberList[pos] = i;
    }
    __threadfence();
    __syncthreads();
    if (tid == 0) atomicExch(flag1, MAGIC1);
    return;

  } else if (bid < B_K5) {
    // ---- zero role: 258 float4 of [1024,133120) each ----
    spin1(flagZ0, MAGICZ);   // zcnt re-initialized
    int b = bid - B_ZERO0;
    char* base = ws + WS_LSEROW + b * 4128;
    float4v z4 = {0.f, 0.f, 0.f, 0.f};
    *(float4v*)(base + tid * 16) = z4;
    if (tid < 2) *(float4v*)(base + (256 + tid) * 16) = z4;
    __threadfence();
    __syncthreads();
    if (tid == 0) atomicAdd(zcnt, 1u);
    spin1(flag1, MAGIC1);    // done2 re-initialized before flag1
    if (tid == 0) atomicAdd(done2, 1u);
    return;

  } else if (bid < B_K2) {
    // ---- k5 role: 64x128 masked sum-of-exp via MFMA f16 (proven body) ----
    int v = bid - B_K5;
    spin2(flag1, MAGIC1, zcnt, 32u);
    int s = v & 63;
    int m = counts[s];
    int g0 = offsets[s];
    int lane = tid & 63, wv = tid >> 6;
    int quad = lane >> 4, cl = lane & 15;
    int rt0 = (v >> 6) & 3, ct0 = (v >> 8) & 1;  // strides 4, 2

    for (int rt = rt0; rt * 64 < m; rt += 4) {
      for (int ct = ct0; ct * 128 < m; ct += 2) {
        __syncthreads();
        if (tid < 192) {
          int base = (tid < 64) ? (rt * 64 + tid) : (ct * 128 + (tid - 64));
          sm.k5.idx[tid] = (base < m) ? memberList[g0 + base] : -1;
        }
        __syncthreads();

        const float* srcB[6];
        bool val[6];
        int dst[6];
        float4 r0[6], r1[6];
        #pragma unroll
        for (int p = 0; p < 6; ++p) {
          int u = p * 256 + tid;
          int isB = u >= 512;
          int vv = isB ? (u - 512) : u;
          int row = vv >> 3, sub = vv & 7;
          int ksl = sub >> 2, q = sub & 3;
          int ridx = sm.k5.idx[isB ? (64 + row) : row];
          val[p] = ridx >= 0;
          srcB[p] = (isB ? tx : sp) + (val[p] ? ridx : 0) * DD + ksl * 32 + q * 8;
          dst[p] = isB ? (512 + (ksl * 128 + row) * 4 + q)
                       : ((ksl * 64 + row) * 4 + q);
        }
        #pragma unroll
        for (int p = 0; p < 6; ++p) {
          r0[p] = *reinterpret_cast<const float4*>(srcB[p]);
          r1[p] = *reinterpret_cast<const float4*>(srcB[p] + 4);
        }

        float4v acc[8];
        #pragma unroll
        for (int cf = 0; cf < 8; ++cf) acc[cf] = (float4v){0.f, 0.f, 0.f, 0.f};

        for (int kc = 0; kc < 4; ++kc) {
          __syncthreads();
          uint4v z4 = (uint4v){0u, 0u, 0u, 0u};
          #pragma unroll
          for (int p = 0; p < 6; ++p)
            sm.k5.frag[dst[p]] = val[p] ? pack8(r0[p], r1[p]) : z4;
          __syncthreads();
          if (kc < 3) {
            #pragma unroll
            for (int p = 0; p < 6; ++p) {
              r0[p] = *reinterpret_cast<const float4*>(srcB[p] + (kc + 1) * 64);
              r1[p] = *reinterpret_cast<const float4*>(srcB[p] + (kc + 1) * 64 + 4);
            }
          }
          #pragma unroll
          for (int ksl = 0; ksl < 2; ++ksl) {
            half8 a = __builtin_bit_cast(half8, sm.k5.frag[(ksl * 64 + wv * 16 + cl) * 4 + quad]);
            #pragma unroll
            for (int cf = 0; cf < 8; ++cf) {
              half8 b = __builtin_bit_cast(half8, sm.k5.frag[512 + (ksl * 128 + cf * 16 + cl) * 4 + quad]);
              acc[cf] = __builtin_amdgcn_mfma_f32_16x16x32_f16(a, b, acc[cf], 0, 0, 0);
            }
          }
        }

        int riBase = rt * 64 + wv * 16 + quad * 4;
        float rowAcc[4] = {0.f, 0.f, 0.f, 0.f};
        #pragma unroll
        for (int cf = 0; cf < 8; ++cf) {
          int ci = ct * 128 + cf * 16 + cl;
          bool cv = ci < m;
          float colAcc = 0.f;
          #pragma unroll
          for (int reg = 0; reg < 4; ++reg) {
            bool rv = (riBase + reg) < m;
            float e = (rv && cv) ? __expf(acc[cf][reg] * (1.f / TAU)) : 0.f;
            rowAcc[reg] += e;
            colAcc += e;
          }
          colAcc += __shfl_xor(colAcc, 16);
          colAcc += __shfl_xor(colAcc, 32);
          if (quad == 0 && cv) atomicAdd(&lseCol[g0 + ci], colAcc);
        }
        #pragma unroll
        for (int reg = 0; reg < 4; ++reg) {
          float vv = rowAcc[reg];
          vv += __shfl_xor(vv, 1);
          vv += __shfl_xor(vv, 2);
          vv += __shfl_xor(vv, 4);
          vv += __shfl_xor(vv, 8);
          if (cl == 0 && (riBase + reg) < m) atomicAdd(&lseRow[g0 + riBase + reg], vv);
        }
      }
    }
    __threadfence();
    __syncthreads();
    if (tid == 0) atomicAdd(done2, 1u);
    return;

  } else if (bid < B_T) {
    // ---- k2 role: per-species text sums Ts[s][d] (proven body) ----
    int v2 = bid - B_K2;
    spin2(flag1, MAGIC1, zcnt, 32u);
    int s = v2 & 63, r = v2 >> 6;
    int m = counts[s], g0 = offsets[s];
    int k0 = (m * r) >> 3, k1e = (m * (r + 1)) >> 3;
    if (k0 < k1e) {
      int d = tid;
      float acc = 0.f;
      int k = k0;
      for (; k + 4 <= k1e; k += 4) {
        int i0 = memberList[g0 + k];
        int i1 = memberList[g0 + k + 1];
        int i2 = memberList[g0 + k + 2];
        int i3 = memberList[g0 + k + 3];
        acc += tx[i0 * DD + d] + tx[i1 * DD + d] + tx[i2 * DD + d] + tx[i3 * DD + d];
      }
      for (; k < k1e; ++k) acc += tx[memberList[g0 + k] * DD + d];
      atomicAdd(&Ts[s * DD + d], acc);
    }
    __threadfence();
    __syncthreads();
    if (tid == 0) atomicAdd(done2, 1u);
    return;

  } else if (bid < B_KC) {
    // ---- T role: sum 32 rows of tx into regs (no deps), then publish ----
    int b = bid - B_T;
    int d = tid;
    const float* base = tx + (b * 32) * DD + d;
    float acc = 0.f;
    #pragma unroll 8
    for (int rr = 0; rr < 32; ++rr) acc += base[rr * DD];
    spin2(flag1, MAGIC1, zcnt, 32u);  // T zeroed; done2 re-initialized
    atomicAdd(&T[d], acc);
    __threadfence();
    __syncthreads();
    if (tid == 0) atomicAdd(done2, 1u);
    return;
  }

  // ---- kC role: dots + CE + triplet + election (proven body, 256-thr form) ----
  {
    int cb = bid - B_KC;
    spin1(flag1, MAGIC1);
    int wv = tid >> 6, lane = tid & 63;
    int g = cb * 4 + wv;
    int i = memberList[g];
    int s = ids[i];
    int m = counts[s];
    float4 a = *reinterpret_cast<const float4*>(sp + i * DD + lane * 4);
    float4 b = *reinterpret_cast<const float4*>(tx + i * DD + lane * 4);
    spin1(done2, N_WORK2);           // Ts/T/lseRow/lseCol complete
    float4 c = *reinterpret_cast<const float4*>(Ts + s * DD + lane * 4);
    float4 tv = *reinterpret_cast<const float4*>(T + lane * 4);
    float dDiag = dot4(a, b);
    float dTs   = dot4(a, c);
    float dT    = dot4(a, tv);
    #pragma unroll
    for (int o = 1; o < 64; o <<= 1) {
      dDiag += __shfl_xor(dDiag, o);
      dTs   += __shfl_xor(dTs, o);
      dT    += __shfl_xor(dT, o);
    }
    if (lane == 0) {
      float term = 0.f, tri = 0.f;
      if (m >= 2) {
        term = (__logf(lseRow[g]) + __logf(lseCol[g]) - 2.f * dDiag * (1.f / TAU)) /
               (2.f * (float)m);
        float posMean = (dTs - dDiag) / fmaxf((float)(m - 1), 1.f);
        float negMean = (dT - dTs) / fmaxf((float)(BB - m), 1.f);
        if (m <= BB - 1) tri = fmaxf(negMean - posMean + MARGIN, 0.f);
      }
      sm.red[wv] = term;
      sm.red[4 + wv] = tri;
    }
    __syncthreads();
    if (tid == 0) {
      atomicAdd(&scalars[1], sm.red[0] + sm.red[1] + sm.red[2] + sm.red[3]);
      atomicAdd(&scalars[0], sm.red[4] + sm.red[5] + sm.red[6] + sm.red[7]);
      __threadfence();
      unsigned prev = atomicAdd(&((unsigned*)scalars)[4], 1u);
      if (prev == (unsigned)(N_KC - 1)) {   // last kC block: finalize
        float fi = atomicAdd(&scalars[1], 0.f);
        float ft = atomicAdd(&scalars[0], 0.f);
        float nv = scalars[2];
        float nvi = scalars[3];
        out[0] = fi / fmaxf(nv, 1.f) + ft / fmaxf(nvi, 1.f);
      }
    }
  }
}

extern "C" void kernel_launch(void* const* d_in, const int* in_sizes, int n_in,
                              void* d_out, int out_size, void* d_ws, size_t ws_size,
                              hipStream_t stream) {
  const float* sp = (const float*)d_in[0];
  const float* tx = (const float*)d_in[1];
  const int* ids = (const int*)d_in[2];
  float* out = (float*)d_out;
  char* ws = (char*)d_ws;

  mega<<<N_TOTAL, 256, 0, stream>>>(sp, tx, ids, ws, out);
}

// Round 8
// 108.164 us; speedup vs baseline: 3.1960x; 3.1960x over previous
//
#include <hip/hip_runtime.h>
#include <hip/hip_fp16.h>

#define TAU 0.07f
#define MARGIN 0.2f
#define NSPEC 64
#define BB 8192
#define DD 256

// ---------------- ws layout (bytes) ----------------
//   0      float scalars[8] [0]=triSum [1]=infoSum [2]=n_valid [3]=n_valid_i [4]=done
//                                        (zeroed by kA block 0, then [2],[3] written)
//   64     int   counts[64]              (kA block 0)
//   320    int   offsets[64]             (kA block 0)
//   1024   float lseRow[8192]  32 KB     (zeroed by kA blocks 1-32; atomic kB)
//   33792  float lseCol[8192]  32 KB     (zeroed by kA blocks 1-32; atomic kB)
//   66560  float Ts[64][256]   64 KB     (zeroed by kA blocks 1-32; atomic kB)
//   132096 float T[256]        1 KB      (plain-written by kB block 1024)
//   133120 int   memberList[8192] 32 KB  (kA block 0)
//   165888 float Tpart[128][256] 128 KB  (plain-written by kA blocks 1-32)
#define WS_SCALARS   0
#define WS_COUNTS    64
#define WS_OFFSETS   320
#define WS_LSEROW    1024
#define WS_LSECOL    33792
#define WS_TS        66560
#define WS_T         132096
#define WS_MEMBER    133120
#define WS_TPART     165888

typedef _Float16 half8 __attribute__((ext_vector_type(8)));
typedef float float4v __attribute__((ext_vector_type(4)));
typedef unsigned int uint4v __attribute__((ext_vector_type(4)));

__device__ __forceinline__ uint4v pack8(float4 a, float4 b) {
  half8 h;
  h[0] = (_Float16)a.x; h[1] = (_Float16)a.y; h[2] = (_Float16)a.z; h[3] = (_Float16)a.w;
  h[4] = (_Float16)b.x; h[5] = (_Float16)b.y; h[6] = (_Float16)b.z; h[7] = (_Float16)b.w;
  return __builtin_bit_cast(uint4v, h);
}

__device__ __forceinline__ float dot4(float4 a, float4 b) {
  return a.x * b.x + a.y * b.y + a.z * b.z + a.w * b.w;
}

// ---- kA: block 0 = histogram/scan/scatter (+scalars zero);
//          blocks 1..32 = zero 128KB accumulators (disjoint) + Tpart partial text sums ----
__global__ void kA(const int* __restrict__ ids, const float* __restrict__ tx,
                   char* __restrict__ ws) {
  int bid = blockIdx.x, tid = threadIdx.x;
  if (bid == 0) {
    int* counts_g = (int*)(ws + WS_COUNTS);
    int* offsets_g = (int*)(ws + WS_OFFSETS);
    int* memberList = (int*)(ws + WS_MEMBER);
    float* scalars = (float*)(ws + WS_SCALARS);
    __shared__ int cnt[NSPEC];
    __shared__ int off[NSPEC];
    if (tid < 8) ((unsigned*)scalars)[tid] = 0u;
    if (tid < NSPEC) cnt[tid] = 0;
    __syncthreads();
    int myS[8], myP[8];
    #pragma unroll
    for (int r = 0; r < 8; ++r) {
      int i = r * 1024 + tid;
      int s = ids[i];
      myS[r] = s;
      myP[r] = atomicAdd(&cnt[s], 1);
    }
    __syncthreads();
    if (tid < NSPEC) {  // exactly wave 0
      int o = 0;
      for (int t = 0; t < NSPEC; ++t) o += (t < tid) ? cnt[t] : 0;
      off[tid] = o;
      offsets_g[tid] = o;
      int c = cnt[tid];
      counts_g[tid] = c;
      unsigned long long bv = __ballot(c >= 2);
      float nvi = (c >= 2 && c <= BB - 1) ? (float)c : 0.f;
      for (int o2 = 1; o2 < 64; o2 <<= 1) nvi += __shfl_xor(nvi, o2);
      if (tid == 0) {
        scalars[2] = (float)__popcll(bv);
        scalars[3] = nvi;
      }
    }
    __syncthreads();
    #pragma unroll
    for (int r = 0; r < 8; ++r) {
      int i = r * 1024 + tid;
      memberList[off[myS[r]] + myP[r]] = i;
    }
  } else {
    int b = bid - 1;  // 0..31
    // zero 4 KB chunk of [lseRow|lseCol|Ts] = [1024, 132096), contiguous 128 KB
    if (tid < 256) {
      float4v z4 = {0.f, 0.f, 0.f, 0.f};
      *(float4v*)(ws + WS_LSEROW + b * 4096 + tid * 16) = z4;
    }
    // Tpart[b*4+q][d] = sum of tx rows [b*256+q*64, b*256+(q+1)*64) at dim d
    float* Tpart = (float*)(ws + WS_TPART);
    int d = tid & 255, q = tid >> 8;
    int row0 = b * 256 + q * 64;
    float acc = 0.f;
    #pragma unroll 8
    for (int rr = 0; rr < 64; ++rr) acc += tx[(row0 + rr) * DD + d];
    Tpart[(b * 4 + q) * DD + d] = acc;
  }
}

// ---- kB: bid<512 = k5 MFMA-LSE (proven); 512..1023 = k2 Ts slices;
//          1024 = T reduce from Tpart ----
__global__ void kB(const float* __restrict__ sp, const float* __restrict__ tx,
                   const int* __restrict__ counts, const int* __restrict__ offsets,
                   const int* __restrict__ memberList, const float* __restrict__ Tpart,
                   float* Ts, float* T, float* lseRow, float* lseCol) {
  __shared__ uint4v frag[1536];  // 24 KB (k5 role)
  __shared__ int idx[192];       // tile row indices: A rows [0,64), B rows [64,192)
  int bid = blockIdx.x;
  int tid = threadIdx.x;

  if (bid == 1024) {
    // ---- T reduce: T[d] = sum_p Tpart[p][d], 128 KB L2-hot ----
    int d = tid;
    float acc = 0.f;
    #pragma unroll 8
    for (int p = 0; p < 128; ++p) acc += Tpart[p * DD + d];
    T[d] = acc;
    return;
  }
  if (bid >= 512) {
    // ---- k2 role: per-species text sums Ts[s][d], batched-gather pipeline ----
    int v2 = bid - 512;
    int s = v2 & 63, r = v2 >> 6;
    int m = counts[s], g0 = offsets[s];
    int k0 = (m * r) >> 3, k1e = (m * (r + 1)) >> 3;
    if (k0 >= k1e) return;
    int d = tid;
    float acc = 0.f;
    int k = k0;
    for (; k + 4 <= k1e; k += 4) {
      int i0 = memberList[g0 + k];
      int i1 = memberList[g0 + k + 1];
      int i2 = memberList[g0 + k + 2];
      int i3 = memberList[g0 + k + 3];
      float a0 = tx[i0 * DD + d];
      float a1 = tx[i1 * DD + d];
      float a2 = tx[i2 * DD + d];
      float a3 = tx[i3 * DD + d];
      acc += a0 + a1 + a2 + a3;
    }
    for (; k < k1e; ++k) acc += tx[memberList[g0 + k] * DD + d];
    atomicAdd(&Ts[s * DD + d], acc);
    return;
  }

  // ---- k5 role: 64x128 masked sum-of-exp via MFMA f16, K=256 in 4 chunks ----
  int s = bid & 63;
  int m = counts[s];
  int g0 = offsets[s];
  int lane = tid & 63, wv = tid >> 6;
  int quad = lane >> 4, cl = lane & 15;
  int rt0 = (bid >> 6) & 3, ct0 = (bid >> 8) & 1;  // strides 4, 2

  for (int rt = rt0; rt * 64 < m; rt += 4) {
    for (int ct = ct0; ct * 128 < m; ct += 2) {
      // tile prologue: hoist member indices to LDS ONCE per tile
      __syncthreads();
      if (tid < 192) {
        int base = (tid < 64) ? (rt * 64 + tid) : (ct * 128 + (tid - 64));
        idx[tid] = (base < m) ? memberList[g0 + base] : -1;
      }
      __syncthreads();

      const float* srcB[6];
      bool val[6];
      int dst[6];
      float4 r0[6], r1[6];
      #pragma unroll
      for (int p = 0; p < 6; ++p) {
        int u = p * 256 + tid;
        int isB = u >= 512;
        int v = isB ? (u - 512) : u;
        int row = v >> 3, sub = v & 7;
        int ksl = sub >> 2, q = sub & 3;
        int ridx = idx[isB ? (64 + row) : row];
        val[p] = ridx >= 0;
        srcB[p] = (isB ? tx : sp) + (val[p] ? ridx : 0) * DD + ksl * 32 + q * 8;
        dst[p] = isB ? (512 + (ksl * 128 + row) * 4 + q)
                     : ((ksl * 64 + row) * 4 + q);
      }
      #pragma unroll
      for (int p = 0; p < 6; ++p) {
        r0[p] = *reinterpret_cast<const float4*>(srcB[p]);
        r1[p] = *reinterpret_cast<const float4*>(srcB[p] + 4);
      }

      float4v acc[8];
      #pragma unroll
      for (int cf = 0; cf < 8; ++cf) acc[cf] = (float4v){0.f, 0.f, 0.f, 0.f};

      for (int kc = 0; kc < 4; ++kc) {
        __syncthreads();
        uint4v z4 = (uint4v){0u, 0u, 0u, 0u};
        #pragma unroll
        for (int p = 0; p < 6; ++p)
          frag[dst[p]] = val[p] ? pack8(r0[p], r1[p]) : z4;
        __syncthreads();
        if (kc < 3) {
          #pragma unroll
          for (int p = 0; p < 6; ++p) {
            r0[p] = *reinterpret_cast<const float4*>(srcB[p] + (kc + 1) * 64);
            r1[p] = *reinterpret_cast<const float4*>(srcB[p] + (kc + 1) * 64 + 4);
          }
        }
        #pragma unroll
        for (int ksl = 0; ksl < 2; ++ksl) {
          half8 a = __builtin_bit_cast(half8, frag[(ksl * 64 + wv * 16 + cl) * 4 + quad]);
          #pragma unroll
          for (int cf = 0; cf < 8; ++cf) {
            half8 b = __builtin_bit_cast(half8, frag[512 + (ksl * 128 + cf * 16 + cl) * 4 + quad]);
            acc[cf] = __builtin_amdgcn_mfma_f32_16x16x32_f16(a, b, acc[cf], 0, 0, 0);
          }
        }
      }

      // epilogue: masked exp, row/col sums
      int riBase = rt * 64 + wv * 16 + quad * 4;
      float rowAcc[4] = {0.f, 0.f, 0.f, 0.f};
      #pragma unroll
      for (int cf = 0; cf < 8; ++cf) {
        int ci = ct * 128 + cf * 16 + cl;
        bool cv = ci < m;
        float colAcc = 0.f;
        #pragma unroll
        for (int reg = 0; reg < 4; ++reg) {
          bool rv = (riBase + reg) < m;
          float e = (rv && cv) ? __expf(acc[cf][reg] * (1.f / TAU)) : 0.f;
          rowAcc[reg] += e;
          colAcc += e;
        }
        colAcc += __shfl_xor(colAcc, 16);
        colAcc += __shfl_xor(colAcc, 32);
        if (quad == 0 && cv) atomicAdd(&lseCol[g0 + ci], colAcc);
      }
      #pragma unroll
      for (int reg = 0; reg < 4; ++reg) {
        float v = rowAcc[reg];
        v += __shfl_xor(v, 1);
        v += __shfl_xor(v, 2);
        v += __shfl_xor(v, 4);
        v += __shfl_xor(v, 8);
        if (cl == 0 && (riBase + reg) < m) atomicAdd(&lseRow[g0 + riBase + reg], v);
      }
    }
  }
}

// ---- kC: fused dots + CE + triplet + done-counter finalize (verbatim, proven) ----
__global__ void kC(const float* __restrict__ sp, const float* __restrict__ tx,
                   const int* __restrict__ ids, const int* __restrict__ counts,
                   const int* __restrict__ memberList,
                   const float* __restrict__ Ts, const float* __restrict__ T,
                   const float* __restrict__ lseRow, const float* __restrict__ lseCol,
                   float* scalars, float* out) {
  __shared__ float red[32];
  int tid = threadIdx.x;
  int gt = blockIdx.x * 1024 + tid;
  int g = gt >> 6, lane = gt & 63;
  int i = memberList[g];
  int s = ids[i];
  int m = counts[s];
  float4 a = *reinterpret_cast<const float4*>(sp + i * DD + lane * 4);
  float4 b = *reinterpret_cast<const float4*>(tx + i * DD + lane * 4);
  float4 c = *reinterpret_cast<const float4*>(Ts + s * DD + lane * 4);
  float4 tv = *reinterpret_cast<const float4*>(T + lane * 4);
  float dDiag = dot4(a, b);
  float dTs   = dot4(a, c);
  float dT    = dot4(a, tv);
  #pragma unroll
  for (int o = 1; o < 64; o <<= 1) {
    dDiag += __shfl_xor(dDiag, o);
    dTs   += __shfl_xor(dTs, o);
    dT    += __shfl_xor(dT, o);
  }
  if (lane == 0) {
    float term = 0.f, tri = 0.f;
    if (m >= 2) {
      term = (__logf(lseRow[g]) + __logf(lseCol[g]) - 2.f * dDiag * (1.f / TAU)) /
             (2.f * (float)m);
      float posMean = (dTs - dDiag) / fmaxf((float)(m - 1), 1.f);
      float negMean = (dT - dTs) / fmaxf((float)(BB - m), 1.f);
      if (m <= BB - 1) tri = fmaxf(negMean - posMean + MARGIN, 0.f);
    }
    int wv = tid >> 6;
    red[wv] = term;
    red[16 + wv] = tri;
  }
  __syncthreads();
  if (tid == 0) {
    float infoS = 0.f, triS = 0.f;
    #pragma unroll
    for (int w = 0; w < 16; ++w) { infoS += red[w]; triS += red[16 + w]; }
    atomicAdd(&scalars[1], infoS);
    atomicAdd(&scalars[0], triS);
    __threadfence();
    unsigned prev = atomicAdd((unsigned*)&scalars[4], 1u);
    if (prev == (unsigned)(gridDim.x - 1)) {
      float fi = atomicAdd(&scalars[1], 0.f);
      float ft = atomicAdd(&scalars[0], 0.f);
      float nv = scalars[2];
      float nvi = scalars[3];
      out[0] = fi / fmaxf(nv, 1.f) + ft / fmaxf(nvi, 1.f);
    }
  }
}

extern "C" void kernel_launch(void* const* d_in, const int* in_sizes, int n_in,
                              void* d_out, int out_size, void* d_ws, size_t ws_size,
                              hipStream_t stream) {
  const float* sp = (const float*)d_in[0];
  const float* tx = (const float*)d_in[1];
  const int* ids = (const int*)d_in[2];
  float* out = (float*)d_out;

  char* ws = (char*)d_ws;
  float* scalars = (float*)(ws + WS_SCALARS);
  int* counts = (int*)(ws + WS_COUNTS);
  int* offsets = (int*)(ws + WS_OFFSETS);
  float* lseRow = (float*)(ws + WS_LSEROW);
  float* lseCol = (float*)(ws + WS_LSECOL);
  float* Ts = (float*)(ws + WS_TS);
  float* T = (float*)(ws + WS_T);
  int* memberList = (int*)(ws + WS_MEMBER);
  float* Tpart = (float*)(ws + WS_TPART);

  kA<<<33, 1024, 0, stream>>>(ids, tx, ws);
  kB<<<1025, 256, 0, stream>>>(sp, tx, counts, offsets, memberList, Tpart,
                               Ts, T, lseRow, lseCol);
  kC<<<512, 1024, 0, stream>>>(sp, tx, ids, counts, memberList, Ts, T,
                               lseRow, lseCol, scalars, out);
}